// Round 17
// baseline (96.352 us; speedup 1.0000x reference)
//
#include <hip/hip_runtime.h>

// ---------- types ----------
typedef __attribute__((ext_vector_type(8))) short short8;     // 8 bf16 (4 VGPRs)
typedef __attribute__((ext_vector_type(4))) float floatx4;    // MFMA C/D
typedef __attribute__((ext_vector_type(4))) unsigned int uintx4;

// ---------- fp32 -> packed bf16x2 (RNE) ----------
#if __has_builtin(__builtin_amdgcn_cvt_pk_bf16_f32)
typedef __attribute__((ext_vector_type(2))) __bf16 bf16x2;
__device__ __forceinline__ unsigned int pk_bf16(float a, float b) {
  bf16x2 v = __builtin_amdgcn_cvt_pk_bf16_f32(a, b);
  return __builtin_bit_cast(unsigned int, v);
}
#else
__device__ __forceinline__ unsigned int bf16_1(float f) {
  unsigned int u = __builtin_bit_cast(unsigned int, f);
  return (u + 0x7fffu + ((u >> 16) & 1u)) >> 16;
}
__device__ __forceinline__ unsigned int pk_bf16(float a, float b) {
  return bf16_1(a) | (bf16_1(b) << 16);
}
#endif

// Fragment conventions (verified rounds 0-16, absmax 3.9e-3):
//   A-frag (16x16x32): lane(ln,quad) holds A[m=ln][k=quad*8+j], j=0..7
//   B-frag:            lane(ln,quad) holds B[n=ln][k=quad*8+j]  (B[k][n]=W[c][r][k], n=r*8+c)
//   C/D:               col=ln, row=quad*4+reg
// Bprep frag id: Fb = ((mod*8 + h)*24 + ks)*4 + nt, n16 = h*4+nt; frag = 64 lanes x 16B.
//
// LEDGER (do not revisit without new evidence):
// * STORE GEOMETRY LOAD-BEARING: 16 consecutive dwords per 16-lane group
//   x 4 rows/instr = 1.0x writes. Anything else 1.5-3.0x.
// * NT STORES: 3x writes (r3). NT LOADS: kill L3 residency (r15 bench).
// * PERMUTED-B + direct stores: silent transpose (r6).
// * REG-SPILL SIGNATURE: WRITE balloon + 2.4x dur (r7).
// * OCCUPANCY 43->76%: zero (r10). PREFETCH 2->3: zero (r11).
//   K-STAGGER: zero (r13). VALU DIET: zero (r14). SC1: null instrument (r16).
// * CONFIRMED MECHANISM (r15 profiled, NT isolation): X streaming evicts B
//   from per-XCD L2 -> B served by L3 -> ~25% cost. No cache flag can give
//   L2-noalloc + L3-alloc simultaneously on gfx950.
// ROUND-17: REGISTER-RESIDENT B. Persistent blocks: each wave holds its
// 32-col B-slice (24ks x 2frags = 192 VGPRs) in registers for its whole
// life and loops over 6-7 row-tiles. B memory traffic 1.2GB -> 196MB
// (once per block); the L2-eviction problem becomes moot (B is in the RF).
// Cost: X read 2x (256-col strips), staging VALU 2x. Net streaming
// ~1.45GB -> ~0.6GB.

// ============================================================
// Prepass W: [8][64][768] fp32 -> bf16 B-fragments; bias permuted to n-order.
// ============================================================
__global__ __launch_bounds__(256) void prep_w(
    const float* __restrict__ Wi, const float* __restrict__ Wc, const float* __restrict__ Wd,
    const float* __restrict__ bi, const float* __restrict__ bc, const float* __restrict__ bd,
    uintx4* __restrict__ Bprep, float* __restrict__ biasPrep) {
  const int t = blockIdx.x * 256 + threadIdx.x;  // 0 .. 147455
  const int l = t & 63;
  const int frag = t >> 6;             // 0 .. 2303
  const int nt = frag & 3;
  const int q = frag >> 2;
  const int ks = q % 24;
  const int q2 = q / 24;
  const int h = q2 & 7;
  const int mod = q2 >> 3;
  const int n16 = h * 4 + nt;
  const float* __restrict__ W = (mod == 0) ? Wi : ((mod == 1) ? Wc : Wd);

  const int n = n16 * 16 + (l & 15);
  const int r = n >> 3;
  const int c = n & 7;
  const int i0 = ks * 32 + (l >> 4) * 8;
  const float* src = W + (size_t)(c * 64 + r) * 768 + i0;
  floatx4 f0 = *(const floatx4*)(src);
  floatx4 f1 = *(const floatx4*)(src + 4);
  uintx4 p;
  p.x = pk_bf16(f0.x, f0.y);
  p.y = pk_bf16(f0.z, f0.w);
  p.z = pk_bf16(f1.x, f1.y);
  p.w = pk_bf16(f1.z, f1.w);
  Bprep[(size_t)frag * 64 + l] = p;

  if (t < 1536) {
    const int m2 = t >> 9;
    const int nn = t & 511;
    const float* bb = (m2 == 0) ? bi : ((m2 == 1) ? bc : bd);
    biasPrep[t] = bb[(nn & 7) * 64 + (nn >> 3)];
  }
}

// ============================================================
// Fused GEMM + squash, REGISTER-RESIDENT B persistent blocks.
//   Grid 510 = 6 strips (3 mods x 2 col-halves, 256 cols each) x 85.
//   Block: 512 thr / 8 waves; wave owns 32 cols: Bfr[48] = 192 VGPRs
//   loaded once; acc[2][2]; 3-deep A prefetch. launch_bounds(512,2)
//   -> 256-reg cap, 2 waves/SIMD, 1 block/CU, 2 rounds of 255.
//   Per job (row-tile rt): stage A (32x768 -> 48 KB LDS, slot-XOR),
//   barrier, unrolled 24-step K-loop (2 ds_read + 4 MFMA per step,
//   ZERO B loads), epilogue (squash + proven 1.0x stores), WAR barrier.
// ============================================================
#define LOADA(aa, kk)                                                        \
  {                                                                          \
    _Pragma("unroll") for (int mt = 0; mt < 2; ++mt)                         \
        aa[mt] = Afr[((kk) * 2 + mt) * 64 +                                  \
                     ((ln ^ (((kk) * 4 + quad) & 15)) + (quad << 4))];       \
  }

#define COMP(aa, kk)                                                     \
  {                                                                      \
    _Pragma("unroll") for (int mt = 0; mt < 2; ++mt)                     \
    {                                                                    \
      short8 af = __builtin_bit_cast(short8, aa[mt]);                    \
      _Pragma("unroll") for (int n2 = 0; n2 < 2; ++n2)                   \
          acc[mt][n2] = __builtin_amdgcn_mfma_f32_16x16x32_bf16(         \
              af, __builtin_bit_cast(short8, Bfr[(kk) * 2 + n2]),        \
              acc[mt][n2], 0, 0, 0);                                     \
    }                                                                    \
  }

__global__ __launch_bounds__(512, 2) void caps_fused(
    const float* __restrict__ x0, const float* __restrict__ x1, const float* __restrict__ x2,
    const uintx4* __restrict__ Bprep, const float* __restrict__ biasPrep,
    float* __restrict__ out) {
  __shared__ unsigned long long As64[48 * 128];  // 48 frags x 64 slots x 16 B

  const int tid = threadIdx.x;
  const int bxx = blockIdx.x;        // 0..509
  const int strip = bxx % 6;         // (mod, col-half)
  const int idx = bxx / 6;           // 0..84: position within strip
  const int mod = strip >> 1;
  const int half = strip & 1;
  const float* __restrict__ X = (mod == 0) ? x0 : ((mod == 1) ? x1 : x2);

  const int lane = tid & 63;
  const int ln = lane & 15;
  const int quad = lane >> 4;
  const int wv = tid >> 6;           // 0..7: n16 pair = half*16 + wv*2 + {0,1}

  // ---- B prologue: load this wave's 48 B-frags into registers (once) ----
  const uintx4* bbase =
      Bprep +
      (size_t)((mod * 8 + half * 4 + (wv >> 1)) * 96 + (wv & 1) * 2) * 64 +
      lane;
  uintx4 Bfr[48];
#pragma unroll
  for (int ks = 0; ks < 24; ++ks)
#pragma unroll
    for (int n2 = 0; n2 < 2; ++n2)
      Bfr[ks * 2 + n2] = bbase[(ks * 4 + n2) * 64];

  const int col0 = mod * 512 + half * 256 + wv * 32 + ln;
  const float bias0 = biasPrep[col0];
  const float bias1 = biasPrep[col0 + 16];

  const uintx4* Afr = (const uintx4*)As64;

#pragma unroll 1
  for (int rt = idx; rt < 512; rt += 85) {
    if (rt != idx) __syncthreads();  // WAR: prev K-loop ds_reads complete

    // ---- stage A: 32 rows x 768 cols fp32 -> bf16 frags (r14 body) ----
    const float* src = X + (size_t)rt * 32 * 768;
#pragma unroll
    for (int i = 0; i < 12; ++i) {
      const int fidx = i * 2048 + tid * 4;       // flat float index in tile
      floatx4 f = *(const floatx4*)(src + fidx);
      const int m = (unsigned)fidx / 768u;
      const int k = fidx - m * 768;
      const int ks = k >> 5;
      const int kk = k & 31;
      const int qk = kk >> 3;                    // quad of k
      const int jh = (kk >> 2) & 1;              // which 8-byte half
      const int mt = m >> 4;
      const int lnn = m & 15;
      const int p = (ks * 4 + qk) & 15;          // slot-XOR spread
      const int slot = (lnn ^ p) + (qk << 4);
      unsigned long long w =
          ((unsigned long long)pk_bf16(f.z, f.w) << 32) | pk_bf16(f.x, f.y);
      As64[(((ks * 2 + mt) * 64 + slot) << 1) + jh] = w;
    }
    __syncthreads();

    // ---- K-loop: 24 steps, 2 ds_read + 4 MFMA each, B from registers ----
    floatx4 acc[2][2];
#pragma unroll
    for (int mt = 0; mt < 2; ++mt)
#pragma unroll
      for (int n2 = 0; n2 < 2; ++n2) acc[mt][n2] = (floatx4)(0.0f);

    uintx4 a0[2], a1[2], a2[2];
    LOADA(a0, 0); LOADA(a1, 1); LOADA(a2, 2);
#pragma unroll
    for (int it = 0; it < 7; ++it) {   // fully unrolled, compile-time ks
      const int s = 3 * it;
      COMP(a0, s);     LOADA(a0, s + 3);
      COMP(a1, s + 1); LOADA(a1, s + 4);
      COMP(a2, s + 2); LOADA(a2, s + 5);
    }
    COMP(a0, 21); COMP(a1, 22); COMP(a2, 23);

    // ---- epilogue: bias + squash + imm-offset stores (1.0x geometry) ----
#pragma unroll
    for (int mt = 0; mt < 2; ++mt) {
      float* opm = out + (size_t)(rt * 32 + mt * 16 + quad * 4) * 1536 + col0;
#pragma unroll
      for (int jj = 0; jj < 4; ++jj) {
        float* opj = opm + jj * 1536;
#pragma unroll
        for (int n2 = 0; n2 < 2; ++n2) {
          float u = acc[mt][n2][jj] + (n2 ? bias1 : bias0);
          float s = u * u;
          s += __shfl_xor(s, 1);
          s += __shfl_xor(s, 2);
          s += __shfl_xor(s, 4);
#if __has_builtin(__builtin_amdgcn_rsqf) && __has_builtin(__builtin_amdgcn_rcpf)
          float sc = s * __builtin_amdgcn_rsqf(s + 1e-7f) *
                     __builtin_amdgcn_rcpf(1.0f + s);
#else
          float sc = s / ((1.0f + s) * sqrtf(s + 1e-7f));
#endif
          opj[n2 * 16] = u * sc;       // 16 consecutive dwords / 16-lane group
        }
      }
    }
  }
}

// ============================================================
extern "C" void kernel_launch(void* const* d_in, const int* in_sizes, int n_in,
                              void* d_out, int out_size, void* d_ws, size_t ws_size,
                              hipStream_t stream) {
  const float* ximg = (const float*)d_in[0];
  const float* xcapt = (const float*)d_in[1];
  const float* xdct = (const float*)d_in[2];
  const float* Wi = (const float*)d_in[3];
  const float* bi = (const float*)d_in[4];
  const float* Wc = (const float*)d_in[5];
  const float* bc = (const float*)d_in[6];
  const float* Wd = (const float*)d_in[7];
  const float* bd = (const float*)d_in[8];

  uintx4* Bprep = (uintx4*)d_ws;                           // 2.25 MiB
  float* biasPrep = (float*)((char*)d_ws + 2304 * 1024);   // 6 KiB

  hipLaunchKernelGGL(prep_w, dim3(576), dim3(256), 0, stream,
                     Wi, Wc, Wd, bi, bc, bd, Bprep, biasPrep);
  hipLaunchKernelGGL(caps_fused, dim3(510), dim3(512), 0, stream,
                     ximg, xcapt, xdct, (const uintx4*)Bprep, biasPrep,
                     (float*)d_out);
}